// Round 4
// baseline (280.770 us; speedup 1.0000x reference)
//
#include <hip/hip_runtime.h>
#include <hip/hip_bf16.h>

// Problem constants
#define BB 4096
#define TT 16
#define HH 768
#define AA 128
#define VV 16
#define LL 2
#define NCHUNK 6        // K chunks of 128 (full K per block)
#define MT 32           // rows per tile (grid <= 143 -> 1 block/CU, single pass)

typedef __attribute__((ext_vector_type(8))) short short8v;   // 8 bf16 (4 VGPRs)
typedef __attribute__((ext_vector_type(4))) float float4v;   // MFMA C/D frag

// ws layout (int indices into d_ws):
//  [0..16]       offs (int)     bucket offsets
//  [64..4159]    rows (int)     bucketed row ids
//  [4160..8255]  Wuc  (float)   [V][A][L] = Wu@Wc^T
//  [8256..8287]  buc  (float)   [V][L]    = bu@Wc^T
//  [8448..]      Wdp  (ushort)  [V][6][A][128] bf16 transposed Wd (dense)
#define WS_OFFS 0
#define WS_ROWS 64
#define WS_WUC  4160
#define WS_BUC  8256
#define WS_WDP  8448

__device__ __forceinline__ unsigned short f2bf(float f) {
    __hip_bfloat16 h = __float2bfloat16(f);   // RNE
    return *reinterpret_cast<unsigned short*>(&h);
}

__device__ __forceinline__ float gelu_tanh(float z) {
    float y = 0.7978845608028654f * (z + 0.044715f * z * z * z);
    y = fminf(fmaxf(y, -15.f), 15.f);
    float e = __expf(2.f * y);
    float th = (e - 1.f) / (e + 1.f);
    return 0.5f * z * (1.f + th);
}

// ---------------- K1: prep (verbatim from the verified version)
// blocks 0..95    : Wdp[v][kc] = bf16 transpose of Wd chunk
// blocks 96..223  : Wuc — 128 blocks, 16 a-columns each (16 thr/col)
// block 224       : buc[v][l] = bu[v] @ Wc^T
// block 225       : bucket rows by variety
__global__ __launch_bounds__(256) void k_prep(
    const int*   __restrict__ variety_ids,
    const float* __restrict__ Wd,   // (V, H, A)
    const float* __restrict__ Wu,   // (V, A, H)
    const float* __restrict__ bu,   // (V, H)
    const float* __restrict__ Wc,   // (L, H)
    int* __restrict__ ws_i)
{
    __shared__ __align__(16) unsigned short Wds[128 * 136];
    __shared__ float sp0[256], sp1[256];
    __shared__ int hist[VV], hoff[VV + 1], hcur[VV];

    const int t = threadIdx.x;
    const int bid = blockIdx.x;
    unsigned short* wdp = (unsigned short*)(ws_i + WS_WDP);
    float* Wuc = (float*)(ws_i + WS_WUC);
    float* buc = (float*)(ws_i + WS_BUC);

    if (bid < 96) {
        // ---- Wd chunk transpose + convert: global [k][a] -> [a][k] ----
        const int v = bid / NCHUNK, kc = bid % NCHUNK;
        const float* wd = Wd + (size_t)v * HH * AA;
        const int ks0 = kc * 128;
        #pragma unroll
        for (int s = 0; s < 16; ++s) {
            int idx = t + s * 256;
            int hl  = idx >> 5;
            int a4  = idx & 31;
            float4 wv = *(const float4*)(wd + (size_t)(ks0 + hl) * AA + a4 * 4);
            Wds[(a4 * 4 + 0) * 136 + hl] = f2bf(wv.x);
            Wds[(a4 * 4 + 1) * 136 + hl] = f2bf(wv.y);
            Wds[(a4 * 4 + 2) * 136 + hl] = f2bf(wv.z);
            Wds[(a4 * 4 + 3) * 136 + hl] = f2bf(wv.w);
        }
        __syncthreads();
        unsigned short* dst = wdp + (size_t)(v * NCHUNK + kc) * AA * 128;
        #pragma unroll
        for (int s = 0; s < 8; ++s) {
            int G = t + s * 256;            // 0..2047
            int a = G >> 4, g = G & 15;     // 16 granules of 8 bf16 per row
            uint4 w = *(const uint4*)&Wds[a * 136 + g * 8];
            *(uint4*)&dst[a * 128 + g * 8] = w;
        }
    } else if (bid < 224) {
        // ---- Wuc: block handles (v, 16-a group); 16 threads per column ----
        const int v = (bid - 96) >> 3;
        const int g = (bid - 96) & 7;
        const int a_loc = t >> 4;           // 0..15
        const int q     = t & 15;           // h segment
        const int a = g * 16 + a_loc;
        const float* wu = Wu + (size_t)v * AA * HH + (size_t)a * HH;
        float s0 = 0.f, s1 = 0.f;
        #pragma unroll 4
        for (int h = q * 48; h < q * 48 + 48; h += 4) {
            float4 w  = *(const float4*)&wu[h];
            float4 c0 = *(const float4*)&Wc[h];
            float4 c1 = *(const float4*)&Wc[HH + h];
            s0 += w.x * c0.x + w.y * c0.y + w.z * c0.z + w.w * c0.w;
            s1 += w.x * c1.x + w.y * c1.y + w.z * c1.z + w.w * c1.w;
        }
        sp0[a_loc * 16 + q] = s0;
        sp1[a_loc * 16 + q] = s1;
        __syncthreads();
        if (t < 16) {
            float r0 = 0.f, r1 = 0.f;
            #pragma unroll
            for (int i = 0; i < 16; ++i) { r0 += sp0[t * 16 + i]; r1 += sp1[t * 16 + i]; }
            int aa = g * 16 + t;
            Wuc[(v * AA + aa) * LL + 0] = r0;
            Wuc[(v * AA + aa) * LL + 1] = r1;
        }
    } else if (bid == 224) {
        // ---- buc[v][l] : 32 pairs x 8 h-segments ----
        const int pair = t >> 3, seg = t & 7;
        const int v = pair >> 1, l = pair & 1;
        float s = 0.f;
        const float* bv = bu + (size_t)v * HH;
        for (int h = seg * 96; h < seg * 96 + 96; ++h) s += bv[h] * Wc[l * HH + h];
        sp0[t] = s;
        __syncthreads();
        if (t < 32) {
            float r = 0.f;
            #pragma unroll
            for (int i = 0; i < 8; ++i) r += sp0[t * 8 + i];
            buc[t] = r;   // t = v*2 + l
        }
    } else {
        // ---- bucketing ----
        if (t < VV) hist[t] = 0;
        __syncthreads();
        for (int b = t; b < BB; b += 256) atomicAdd(&hist[variety_ids[b]], 1);
        __syncthreads();
        if (t == 0) {
            int s = 0;
            for (int i = 0; i < VV; ++i) { hoff[i] = s; s += hist[i]; }
            hoff[VV] = s;
            for (int i = 0; i <= VV; ++i) ws_i[WS_OFFS + i] = hoff[i];
        }
        __syncthreads();
        if (t < VV) hcur[t] = hoff[t];
        __syncthreads();
        for (int b = t; b < BB; b += 256) {
            int v = variety_ids[b];
            int p = atomicAdd(&hcur[v], 1);
            ws_i[WS_ROWS + p] = b;
        }
    }
}

// ---------------- K2: barrier-free main loop.
// 32 rows/block, 512 threads = 2 row-groups x 4 a-quarter waves.
// A-fragments built in-register from global fp32 (L1-hot, 32B/lane contiguous);
// B-fragments direct from pre-transposed global bf16 (L2-hot). Both pipelined
// one chunk ahead. No LDS and no __syncthreads in the chunk loop.
__global__ __launch_bounds__(512) void k_main(
    const float* __restrict__ last_hidden,
    const int*   __restrict__ ws_i,
    const float* __restrict__ bd,   // (V, A)
    const float* __restrict__ Wc,   // (L, H)
    const float* __restrict__ bc,   // (L,)
    float* __restrict__ out)        // (B, L)
{
    __shared__ __align__(16) float p_part[MT * LL * 64];   // 16 KB partials
    __shared__ int srows[MT];
    __shared__ float xc[MT * LL];

    const int* offs = ws_i + WS_OFFS;
    const int* rows = ws_i + WS_ROWS;
    const float* Wuc = (const float*)(ws_i + WS_WUC);
    const float* buc = (const float*)(ws_i + WS_BUC);
    const unsigned short* wdp = (const unsigned short*)(ws_i + WS_WDP);
    const int t = threadIdx.x;

    // tile -> (variety, local tile)
    const int rt = blockIdx.x;
    int v = -1, tloc = 0, cnt = 0, obase = 0, acc_t = 0;
    for (int vv = 0; vv < VV; ++vv) {
        int c  = offs[vv + 1] - offs[vv];
        int nt = (c + MT - 1) / MT;
        if (rt < acc_t + nt) {
            v = vv; tloc = rt - acc_t;
            cnt = c - tloc * MT; if (cnt > MT) cnt = MT;
            obase = offs[vv];
            break;
        }
        acc_t += nt;
    }
    if (v < 0) return;

    if (t < MT) {
        int rr = t < cnt ? t : cnt - 1;
        srows[t] = rows[obase + tloc * MT + rr];
    }
    __syncthreads();

    const int lane = t & 63;
    const int wid  = t >> 6;
    const int grp  = wid >> 2;            // row-group: rows grp*16 .. grp*16+15
    const int wq   = wid & 3;             // a-quarter
    const int ac0  = wq * 32;
    const int m = lane & 15, quad = lane >> 4;

    // per-lane base pointers
    const float* xb = last_hidden + (size_t)srows[grp * 16 + m] * TT * HH + quad * 8;
    const unsigned short* wdv = wdp + (size_t)v * NCHUNK * AA * 128;
    const unsigned short* bp0 = wdv + (size_t)(ac0 + m)      * 128 + quad * 8;
    const unsigned short* bp1 = wdv + (size_t)(ac0 + 16 + m) * 128 + quad * 8;
    const float* cfp = Wc + (size_t)m * HH + quad * 8;   // used when wq==0 && m<LL

    float4v acc[2];                        // a-cols ac0 + j*16 + m
    float4v accx;                          // classifier side (wq==0 waves)
    acc[0] = (float4v){0.f, 0.f, 0.f, 0.f};
    acc[1] = (float4v){0.f, 0.f, 0.f, 0.f};
    accx   = (float4v){0.f, 0.f, 0.f, 0.f};

    // prologue: issue chunk 0 loads (X 32B/lane x4 steps + B fragments)
    float4 xn[8];
    short8v Bn[8];
    #pragma unroll
    for (int i = 0; i < 4; ++i) {
        xn[2 * i]     = *(const float4*)(xb + i * 32);
        xn[2 * i + 1] = *(const float4*)(xb + i * 32 + 4);
        Bn[i]     = *(const short8v*)(bp0 + i * 32);
        Bn[4 + i] = *(const short8v*)(bp1 + i * 32);
    }

    #pragma unroll
    for (int kc = 0; kc < NCHUNK; ++kc) {
        // rotate pipeline registers (SSA renames under full unroll)
        float4 xcur[8];
        short8v Bc[8];
        #pragma unroll
        for (int i = 0; i < 8; ++i) { xcur[i] = xn[i]; Bc[i] = Bn[i]; }

        // issue next-chunk loads BEFORE compute (stay in flight under MFMAs)
        if (kc + 1 < NCHUNK) {
            const int base = (kc + 1) * 128;
            #pragma unroll
            for (int i = 0; i < 4; ++i) {
                xn[2 * i]     = *(const float4*)(xb + base + i * 32);
                xn[2 * i + 1] = *(const float4*)(xb + base + i * 32 + 4);
                Bn[i]     = *(const short8v*)(bp0 + (size_t)(kc + 1) * AA * 128 + i * 32);
                Bn[4 + i] = *(const short8v*)(bp1 + (size_t)(kc + 1) * AA * 128 + i * 32);
            }
        }

        // classifier B-frags: wq==0 waves, lanes m<2 read L1-hot Wc (fp32)
        float4 cfa[8];
        if (wq == 0 && m < LL) {
            #pragma unroll
            for (int i = 0; i < 4; ++i) {
                cfa[2 * i]     = *(const float4*)(cfp + kc * 128 + i * 32);
                cfa[2 * i + 1] = *(const float4*)(cfp + kc * 128 + i * 32 + 4);
            }
        }

        #pragma unroll
        for (int i = 0; i < 4; ++i) {
            // build A-frag in-register: row (grp*16+m), k = kc*128 + i*32 + quad*8 + j
            float4 a0 = xcur[2 * i], a1 = xcur[2 * i + 1];
            short8v af;
            af[0] = (short)f2bf(a0.x); af[1] = (short)f2bf(a0.y);
            af[2] = (short)f2bf(a0.z); af[3] = (short)f2bf(a0.w);
            af[4] = (short)f2bf(a1.x); af[5] = (short)f2bf(a1.y);
            af[6] = (short)f2bf(a1.z); af[7] = (short)f2bf(a1.w);

            acc[0] = __builtin_amdgcn_mfma_f32_16x16x32_bf16(af, Bc[i],     acc[0], 0, 0, 0);
            acc[1] = __builtin_amdgcn_mfma_f32_16x16x32_bf16(af, Bc[4 + i], acc[1], 0, 0, 0);
            if (wq == 0) {
                short8v cf = (short8v){0, 0, 0, 0, 0, 0, 0, 0};
                if (m < LL) {
                    float4 c0 = cfa[2 * i], c1 = cfa[2 * i + 1];
                    cf[0] = (short)f2bf(c0.x); cf[1] = (short)f2bf(c0.y);
                    cf[2] = (short)f2bf(c0.z); cf[3] = (short)f2bf(c0.w);
                    cf[4] = (short)f2bf(c1.x); cf[5] = (short)f2bf(c1.y);
                    cf[6] = (short)f2bf(c1.z); cf[7] = (short)f2bf(c1.w);
                }
                accx = __builtin_amdgcn_mfma_f32_16x16x32_bf16(af, cf, accx, 0, 0, 0);
            }
        }
    }

    // epilogue: z += bd -> gelu -> per-lane partial of sum_a h*Wuc
    {
        float bdv[2], w0v[2], w1v[2];
        #pragma unroll
        for (int j = 0; j < 2; ++j) {
            int a = ac0 + j * 16 + m;
            bdv[j] = bd[v * AA + a];
            w0v[j] = Wuc[(v * AA + a) * LL + 0];
            w1v[j] = Wuc[(v * AA + a) * LL + 1];
        }
        #pragma unroll
        for (int reg = 0; reg < 4; ++reg) {
            int row = grp * 16 + quad * 4 + reg;   // global row within tile
            float p0 = 0.f, p1 = 0.f;
            #pragma unroll
            for (int j = 0; j < 2; ++j) {
                float h = gelu_tanh(acc[j][reg] + bdv[j]);
                p0 += h * w0v[j];
                p1 += h * w1v[j];
            }
            p_part[(row * LL + 0) * 64 + wq * 16 + m] = p0;
            p_part[(row * LL + 1) * 64 + wq * 16 + m] = p1;
        }
        // classifier side-block: col m (<2) of accx is logit l = m
        if (wq == 0 && m < LL) {
            #pragma unroll
            for (int reg = 0; reg < 4; ++reg) {
                int row = grp * 16 + quad * 4 + reg;
                xc[row * LL + m] = accx[reg];
            }
        }
    }
    __syncthreads();

    // final: one thread per (row, l)
    if (t < MT * LL) {
        int row = t >> 1, l = t & 1;
        if (row < cnt) {
            float s = 0.f;
            #pragma unroll
            for (int k = 0; k < 64; ++k) s += p_part[(row * LL + l) * 64 + k];
            int gr = srows[row];
            out[(size_t)gr * LL + l] = s + xc[row * LL + l] + buc[v * LL + l] + bc[l];
        }
    }
}

extern "C" void kernel_launch(void* const* d_in, const int* in_sizes, int n_in,
                              void* d_out, int out_size, void* d_ws, size_t ws_size,
                              hipStream_t stream) {
    const float* last_hidden = (const float*)d_in[0];
    const int*   variety_ids = (const int*)d_in[2];
    const float* Wd = (const float*)d_in[3];
    const float* bd = (const float*)d_in[4];
    const float* Wu = (const float*)d_in[5];
    const float* bu = (const float*)d_in[6];
    const float* Wc = (const float*)d_in[7];
    const float* bc = (const float*)d_in[8];
    float* out = (float*)d_out;

    int* ws_i = (int*)d_ws;

    k_prep<<<226, 256, 0, stream>>>(variety_ids, Wd, Wu, bu, Wc, ws_i);
    // max tiles = sum_v ceil(cnt_v/32) <= 143; launch 144 for margin
    k_main<<<144, 512, 0, stream>>>(last_hidden, ws_i, bd, Wc, bc, out);
}

// Round 5
// 270.600 us; speedup vs baseline: 1.0376x; 1.0376x over previous
//
#include <hip/hip_runtime.h>
#include <hip/hip_bf16.h>

// Problem constants
#define BB 4096
#define TT 16
#define HH 768
#define AA 128
#define VV 16
#define LL 2
#define NCHUNK 6        // K chunks of 128 (full K per block)
#define MT 16           // rows per tile (parallelism: up to 271 blocks)

typedef __attribute__((ext_vector_type(8))) short short8v;   // 8 bf16 (4 VGPRs)
typedef __attribute__((ext_vector_type(4))) float float4v;   // MFMA C/D frag

// ws layout (int indices into d_ws):
//  [0..16]       offs (int)     bucket offsets
//  [64..4159]    rows (int)     bucketed row ids
//  [4160..8255]  Wuc  (float)   [V][A][L] = Wu@Wc^T
//  [8256..8287]  buc  (float)   [V][L]    = bu@Wc^T
//  [8448..]      Wdp  (ushort)  [V][6][A][128] bf16 transposed Wd (dense)
#define WS_OFFS 0
#define WS_ROWS 64
#define WS_WUC  4160
#define WS_BUC  8256
#define WS_WDP  8448

__device__ __forceinline__ unsigned short f2bf(float f) {
    __hip_bfloat16 h = __float2bfloat16(f);   // RNE
    return *reinterpret_cast<unsigned short*>(&h);
}

__device__ __forceinline__ float gelu_tanh(float z) {
    float y = 0.7978845608028654f * (z + 0.044715f * z * z * z);
    y = fminf(fmaxf(y, -15.f), 15.f);
    float e = __expf(2.f * y);
    float th = (e - 1.f) / (e + 1.f);
    return 0.5f * z * (1.f + th);
}

// ---------------- K1: prep
// blocks 0..95    : Wdp[v][kc] = bf16 transpose of Wd chunk
// blocks 96..223  : Wuc — 128 blocks, 16 a-columns each (16 thr/col)
// block 224       : buc[v][l] = bu[v] @ Wc^T
// block 225       : bucket rows by variety
__global__ __launch_bounds__(256) void k_prep(
    const int*   __restrict__ variety_ids,
    const float* __restrict__ Wd,   // (V, H, A)
    const float* __restrict__ Wu,   // (V, A, H)
    const float* __restrict__ bu,   // (V, H)
    const float* __restrict__ Wc,   // (L, H)
    int* __restrict__ ws_i)
{
    __shared__ __align__(16) unsigned short Wds[128 * 136];
    __shared__ float sp0[256], sp1[256];
    __shared__ int hist[VV], hoff[VV + 1], hcur[VV];

    const int t = threadIdx.x;
    const int bid = blockIdx.x;
    unsigned short* wdp = (unsigned short*)(ws_i + WS_WDP);
    float* Wuc = (float*)(ws_i + WS_WUC);
    float* buc = (float*)(ws_i + WS_BUC);

    if (bid < 96) {
        // ---- Wd chunk transpose + convert: global [k][a] -> [a][k] ----
        const int v = bid / NCHUNK, kc = bid % NCHUNK;
        const float* wd = Wd + (size_t)v * HH * AA;
        const int ks0 = kc * 128;
        #pragma unroll
        for (int s = 0; s < 16; ++s) {
            int idx = t + s * 256;
            int hl  = idx >> 5;
            int a4  = idx & 31;
            float4 wv = *(const float4*)(wd + (size_t)(ks0 + hl) * AA + a4 * 4);
            Wds[(a4 * 4 + 0) * 136 + hl] = f2bf(wv.x);
            Wds[(a4 * 4 + 1) * 136 + hl] = f2bf(wv.y);
            Wds[(a4 * 4 + 2) * 136 + hl] = f2bf(wv.z);
            Wds[(a4 * 4 + 3) * 136 + hl] = f2bf(wv.w);
        }
        __syncthreads();
        unsigned short* dst = wdp + (size_t)(v * NCHUNK + kc) * AA * 128;
        #pragma unroll
        for (int s = 0; s < 8; ++s) {
            int G = t + s * 256;            // 0..2047
            int a = G >> 4, g = G & 15;     // 16 granules of 8 bf16 per row
            uint4 w = *(const uint4*)&Wds[a * 136 + g * 8];
            *(uint4*)&dst[a * 128 + g * 8] = w;
        }
    } else if (bid < 224) {
        // ---- Wuc: block handles (v, 16-a group); 16 threads per column ----
        const int v = (bid - 96) >> 3;
        const int g = (bid - 96) & 7;
        const int a_loc = t >> 4;           // 0..15
        const int q     = t & 15;           // h segment
        const int a = g * 16 + a_loc;
        const float* wu = Wu + (size_t)v * AA * HH + (size_t)a * HH;
        float s0 = 0.f, s1 = 0.f;
        #pragma unroll 4
        for (int h = q * 48; h < q * 48 + 48; h += 4) {
            float4 w  = *(const float4*)&wu[h];
            float4 c0 = *(const float4*)&Wc[h];
            float4 c1 = *(const float4*)&Wc[HH + h];
            s0 += w.x * c0.x + w.y * c0.y + w.z * c0.z + w.w * c0.w;
            s1 += w.x * c1.x + w.y * c1.y + w.z * c1.z + w.w * c1.w;
        }
        sp0[a_loc * 16 + q] = s0;
        sp1[a_loc * 16 + q] = s1;
        __syncthreads();
        if (t < 16) {
            float r0 = 0.f, r1 = 0.f;
            #pragma unroll
            for (int i = 0; i < 16; ++i) { r0 += sp0[t * 16 + i]; r1 += sp1[t * 16 + i]; }
            int aa = g * 16 + t;
            Wuc[(v * AA + aa) * LL + 0] = r0;
            Wuc[(v * AA + aa) * LL + 1] = r1;
        }
    } else if (bid == 224) {
        // ---- buc[v][l] : 32 pairs x 8 h-segments ----
        const int pair = t >> 3, seg = t & 7;
        const int v = pair >> 1, l = pair & 1;
        float s = 0.f;
        const float* bv = bu + (size_t)v * HH;
        for (int h = seg * 96; h < seg * 96 + 96; ++h) s += bv[h] * Wc[l * HH + h];
        sp0[t] = s;
        __syncthreads();
        if (t < 32) {
            float r = 0.f;
            #pragma unroll
            for (int i = 0; i < 8; ++i) r += sp0[t * 8 + i];
            buc[t] = r;   // t = v*2 + l
        }
    } else {
        // ---- bucketing ----
        if (t < VV) hist[t] = 0;
        __syncthreads();
        for (int b = t; b < BB; b += 256) atomicAdd(&hist[variety_ids[b]], 1);
        __syncthreads();
        if (t == 0) {
            int s = 0;
            for (int i = 0; i < VV; ++i) { hoff[i] = s; s += hist[i]; }
            hoff[VV] = s;
            for (int i = 0; i <= VV; ++i) ws_i[WS_OFFS + i] = hoff[i];
        }
        __syncthreads();
        if (t < VV) hcur[t] = hoff[t];
        __syncthreads();
        for (int b = t; b < BB; b += 256) {
            int v = variety_ids[b];
            int p = atomicAdd(&hcur[v], 1);
            ws_i[WS_ROWS + p] = b;
        }
    }
}

// ---------------- K2: fused main — B-fragments direct from global (Wdp is
// already in fragment layout [a][k]), software-pipelined one chunk ahead.
// Single barrier per chunk; X double-buffered in LDS; no Wd/Wc LDS staging.
__global__ __launch_bounds__(256) void k_main(
    const float* __restrict__ last_hidden,
    const int*   __restrict__ ws_i,
    const float* __restrict__ bd,   // (V, A)
    const float* __restrict__ Wc,   // (L, H)
    const float* __restrict__ bc,   // (L,)
    float* __restrict__ out)        // (B, L)
{
    __shared__ __align__(16) unsigned short Xs[2][MT * 136];  // double-buffered A tile
    __shared__ __align__(16) float p_part[MT * LL * 64];      // 8 KB partials
    __shared__ int srows[MT];
    __shared__ float xc[MT * LL];

    const int* offs = ws_i + WS_OFFS;
    const int* rows = ws_i + WS_ROWS;
    const float* Wuc = (const float*)(ws_i + WS_WUC);
    const float* buc = (const float*)(ws_i + WS_BUC);
    const unsigned short* wdp = (const unsigned short*)(ws_i + WS_WDP);
    const int t = threadIdx.x;

    // tile -> (variety, local tile)
    const int rt = blockIdx.x;
    int v = -1, tloc = 0, cnt = 0, obase = 0, acc_t = 0;
    for (int vv = 0; vv < VV; ++vv) {
        int c  = offs[vv + 1] - offs[vv];
        int nt = (c + MT - 1) / MT;
        if (rt < acc_t + nt) {
            v = vv; tloc = rt - acc_t;
            cnt = c - tloc * MT; if (cnt > MT) cnt = MT;
            obase = offs[vv];
            break;
        }
        acc_t += nt;
    }
    if (v < 0) return;

    if (t < MT) {
        int rr = t < cnt ? t : cnt - 1;
        srows[t] = rows[obase + tloc * MT + rr];
    }
    __syncthreads();

    const int lane = t & 63;
    const int wv_  = t >> 6;              // 0..3: a-quarter
    const int ac0  = wv_ * 32;
    const int m = lane & 15, quad = lane >> 4;
    const int r0 = t >> 5, k4 = t & 31;   // X staging assignment (2 rows/thread)

    // per-lane base pointers
    const float* xb0 = last_hidden + (size_t)srows[r0]     * TT * HH + k4 * 4;
    const float* xb1 = last_hidden + (size_t)srows[r0 + 8] * TT * HH + k4 * 4;
    const unsigned short* wdv = wdp + (size_t)v * NCHUNK * AA * 128;
    const unsigned short* bp0 = wdv + (size_t)(ac0 + m)      * 128 + quad * 8;
    const unsigned short* bp1 = wdv + (size_t)(ac0 + 16 + m) * 128 + quad * 8;
    const float* cfp = Wc + (size_t)m * HH + quad * 8;   // only used when wv_==0 && m<LL

    float4v acc[2];                        // a-cols ac0 + j*16 + m
    float4v accx;                          // classifier side (wave 0)
    acc[0] = (float4v){0.f, 0.f, 0.f, 0.f};
    acc[1] = (float4v){0.f, 0.f, 0.f, 0.f};
    accx   = (float4v){0.f, 0.f, 0.f, 0.f};

    // prologue: issue chunk 0 loads (X rows + B fragments)
    float4 xA = *(const float4*)xb0;
    float4 xB = *(const float4*)xb1;
    short8v Bn[8];
    #pragma unroll
    for (int i = 0; i < 4; ++i) {
        Bn[i]     = *(const short8v*)(bp0 + i * 32);
        Bn[4 + i] = *(const short8v*)(bp1 + i * 32);
    }

    #pragma unroll
    for (int kc = 0; kc < NCHUNK; ++kc) {
        // rotate pipeline registers (SSA renames under full unroll)
        float4 xAc = xA, xBc = xB;
        short8v Bc[8];
        #pragma unroll
        for (int i = 0; i < 8; ++i) Bc[i] = Bn[i];

        // issue next-chunk loads BEFORE the barrier (stay in flight across it)
        if (kc + 1 < NCHUNK) {
            xA = *(const float4*)(xb0 + (kc + 1) * 128);
            xB = *(const float4*)(xb1 + (kc + 1) * 128);
            #pragma unroll
            for (int i = 0; i < 4; ++i) {
                Bn[i]     = *(const short8v*)(bp0 + (size_t)(kc + 1) * AA * 128 + i * 32);
                Bn[4 + i] = *(const short8v*)(bp1 + (size_t)(kc + 1) * AA * 128 + i * 32);
            }
        }

        // stage X(kc): cvt fp32->bf16, write to Xs[kc&1]
        unsigned short* xs = (unsigned short*)Xs[kc & 1];
        {
            unsigned int q0 = (unsigned)f2bf(xAc.x) | ((unsigned)f2bf(xAc.y) << 16);
            unsigned int q1 = (unsigned)f2bf(xAc.z) | ((unsigned)f2bf(xAc.w) << 16);
            *(uint2*)&xs[r0 * 136 + k4 * 4] = make_uint2(q0, q1);
            q0 = (unsigned)f2bf(xBc.x) | ((unsigned)f2bf(xBc.y) << 16);
            q1 = (unsigned)f2bf(xBc.z) | ((unsigned)f2bf(xBc.w) << 16);
            *(uint2*)&xs[(r0 + 8) * 136 + k4 * 4] = make_uint2(q0, q1);
        }
        __syncthreads();   // single barrier per chunk (double-buffered Xs)

        // classifier B-frags: wave 0, lanes m<2 read L2-hot Wc (fp32)
        float4 cfa[8];
        if (wv_ == 0 && m < LL) {
            #pragma unroll
            for (int i = 0; i < 4; ++i) {
                cfa[2 * i]     = *(const float4*)(cfp + kc * 128 + i * 32);
                cfa[2 * i + 1] = *(const float4*)(cfp + kc * 128 + i * 32 + 4);
            }
        }

        #pragma unroll
        for (int i = 0; i < 4; ++i) {
            short8v af = *(const short8v*)&xs[m * 136 + i * 32 + quad * 8];
            acc[0] = __builtin_amdgcn_mfma_f32_16x16x32_bf16(af, Bc[i],     acc[0], 0, 0, 0);
            acc[1] = __builtin_amdgcn_mfma_f32_16x16x32_bf16(af, Bc[4 + i], acc[1], 0, 0, 0);
            if (wv_ == 0) {
                short8v cf = (short8v){0, 0, 0, 0, 0, 0, 0, 0};
                if (m < LL) {
                    float4 c0 = cfa[2 * i], c1 = cfa[2 * i + 1];
                    cf[0] = (short)f2bf(c0.x); cf[1] = (short)f2bf(c0.y);
                    cf[2] = (short)f2bf(c0.z); cf[3] = (short)f2bf(c0.w);
                    cf[4] = (short)f2bf(c1.x); cf[5] = (short)f2bf(c1.y);
                    cf[6] = (short)f2bf(c1.z); cf[7] = (short)f2bf(c1.w);
                }
                accx = __builtin_amdgcn_mfma_f32_16x16x32_bf16(af, cf, accx, 0, 0, 0);
            }
        }
    }

    // epilogue: z += bd -> gelu -> per-lane partial of sum_a h*Wuc
    {
        float bdv[2], w0v[2], w1v[2];
        #pragma unroll
        for (int j = 0; j < 2; ++j) {
            int a = ac0 + j * 16 + m;
            bdv[j] = bd[v * AA + a];
            w0v[j] = Wuc[(v * AA + a) * LL + 0];
            w1v[j] = Wuc[(v * AA + a) * LL + 1];
        }
        #pragma unroll
        for (int reg = 0; reg < 4; ++reg) {
            int row = quad * 4 + reg;
            float p0 = 0.f, p1 = 0.f;
            #pragma unroll
            for (int j = 0; j < 2; ++j) {
                float h = gelu_tanh(acc[j][reg] + bdv[j]);
                p0 += h * w0v[j];
                p1 += h * w1v[j];
            }
            p_part[(row * LL + 0) * 64 + wv_ * 16 + m] = p0;
            p_part[(row * LL + 1) * 64 + wv_ * 16 + m] = p1;
        }
        // classifier side-block: col m (<2) of accx is logit l = m
        if (wv_ == 0 && m < LL) {
            #pragma unroll
            for (int reg = 0; reg < 4; ++reg) {
                int row = quad * 4 + reg;
                xc[row * LL + m] = accx[reg];
            }
        }
    }
    __syncthreads();

    // final: one thread per (row, l)
    if (t < MT * LL) {
        int row = t >> 1, l = t & 1;
        if (row < cnt) {
            float s = 0.f;
            #pragma unroll
            for (int k = 0; k < 64; ++k) s += p_part[(row * LL + l) * 64 + k];
            int gr = srows[row];
            out[(size_t)gr * LL + l] = s + xc[row * LL + l] + buc[v * LL + l] + bc[l];
        }
    }
}

extern "C" void kernel_launch(void* const* d_in, const int* in_sizes, int n_in,
                              void* d_out, int out_size, void* d_ws, size_t ws_size,
                              hipStream_t stream) {
    const float* last_hidden = (const float*)d_in[0];
    const int*   variety_ids = (const int*)d_in[2];
    const float* Wd = (const float*)d_in[3];
    const float* bd = (const float*)d_in[4];
    const float* Wu = (const float*)d_in[5];
    const float* bu = (const float*)d_in[6];
    const float* Wc = (const float*)d_in[7];
    const float* bc = (const float*)d_in[8];
    float* out = (float*)d_out;

    int* ws_i = (int*)d_ws;

    k_prep<<<226, 256, 0, stream>>>(variety_ids, Wd, Wu, bu, Wc, ws_i);
    // max tiles = sum_v ceil(cnt_v/16) <= 4096/16 + 15 = 271
    k_main<<<271, 256, 0, stream>>>(last_hidden, ws_i, bd, Wc, bc, out);
}